// Round 11
// baseline (362.183 us; speedup 1.0000x reference)
//
#include <hip/hip_runtime.h>
#include <math.h>

#define NEG_SLOPE 0.2f
#define BKT_SHIFT 8            // 256 nodes per bucket
#define EPB 8192               // edges per phase-A block
#define MAXB 10240             // record capacity per bucket region

__device__ __forceinline__ unsigned encf(float f) {
    unsigned u = __float_as_uint(f);
    return (u & 0x80000000u) ? ~u : (u | 0x80000000u);
}
__device__ __forceinline__ float decf(unsigned e) {
    unsigned u = (e & 0x80000000u) ? (e & 0x7FFFFFFFu) : ~e;
    return __uint_as_float(u);
}
__device__ __forceinline__ float lrelu(float t) { return fmaxf(t, NEG_SLOPE * t); }

// ---------------- node transform for conv1: h1 = x@W1, a_src1, a_dst1 ----------------
__global__ void k_node1(const float* __restrict__ x, const float* __restrict__ W1,
                        const float* __restrict__ as1, const float* __restrict__ ad1,
                        float* __restrict__ h1, float* __restrict__ a_src1,
                        float* __restrict__ a_dst1, int N) {
    int n = blockIdx.x * blockDim.x + threadIdx.x;
    if (n >= N) return;
    float xv[8];
#pragma unroll
    for (int k = 0; k < 8; k++) xv[k] = x[n * 8 + k];
    float h[32];
#pragma unroll
    for (int j = 0; j < 32; j++) {
        float acc = 0.f;
#pragma unroll
        for (int k = 0; k < 8; k++) acc += xv[k] * W1[k * 32 + j];
        h[j] = acc;
        h1[n * 32 + j] = acc;
    }
#pragma unroll
    for (int hh = 0; hh < 2; hh++) {
        float s = 0.f, d = 0.f;
#pragma unroll
        for (int c = 0; c < 16; c++) {
            s += h[hh * 16 + c] * as1[hh * 16 + c];
            d += h[hh * 16 + c] * ad1[hh * 16 + c];
        }
        a_src1[n * 2 + hh] = s;
        a_dst1[n * 2 + hh] = d;
    }
}

// ---------------- global per-head max of a_src (order-preserving uint encoding) ----------------
__global__ void k_amax(const float* __restrict__ a, unsigned* __restrict__ outmax, int N) {
    int lane = threadIdx.x & 63;
    float mA = -1e30f, mB = -1e30f;
    for (int i = blockIdx.x * blockDim.x + threadIdx.x; i < N; i += gridDim.x * blockDim.x) {
        float2 v = *(const float2*)(a + 2 * (size_t)i);
        mA = fmaxf(mA, v.x); mB = fmaxf(mB, v.y);
    }
#pragma unroll
    for (int off = 32; off >= 1; off >>= 1) {
        mA = fmaxf(mA, __shfl_xor(mA, off));
        mB = fmaxf(mB, __shfl_xor(mB, off));
    }
    if (lane == 0) {
        atomicMax(&outmax[0], encf(mA));
        atomicMax(&outmax[1], encf(mB));
    }
}

// ---------------- CSR build, phase A (R10 verbatim) ----------------
__global__ __launch_bounds__(256) void k_bktA(const int* __restrict__ ei,
                                              int* __restrict__ bktCur,
                                              int2* __restrict__ bktbuf, int E, int K) {
    __shared__ int bh[256];
    __shared__ int bbase[256];
    __shared__ int loff[256];
    __shared__ int2 staged[EPB];
    __shared__ int gptr[EPB];
    int tid = threadIdx.x;
    int e0 = blockIdx.x * EPB;
    int e1 = e0 + EPB; if (e1 > E) e1 = E;
    int cnt = e1 - e0;
    bh[tid] = 0;
    __syncthreads();
    for (int i = e0 + tid; i < e1; i += 256)
        atomicAdd(&bh[ei[E + i] >> BKT_SHIFT], 1);
    __syncthreads();
    if (tid == 0) {
        int r = 0;
        for (int b = 0; b < K; b++) { loff[b] = r; r += bh[b]; }
    }
    if (tid < K) {
        int c = bh[tid];
        bbase[tid] = c > 0 ? atomicAdd(&bktCur[tid], c) : 0;
    }
    __syncthreads();
    bh[tid] = 0;
    __syncthreads();
    for (int i = e0 + tid; i < e1; i += 256) {
        int s = ei[i], d = ei[E + i];
        int b = d >> BKT_SHIFT, dl = d & 255;
        int r = atomicAdd(&bh[b], 1);
        int lp = loff[b] + r;
        staged[lp] = make_int2(s | (dl << 16), i);
        gptr[lp] = b * MAXB + bbase[b] + r;
    }
    __syncthreads();
    for (int i = tid; i < cnt; i += 256)
        bktbuf[gptr[i]] = staged[i];
}

// ---------------- bucket-size exclusive scan (R10 verbatim) ----------------
__global__ void k_bktscan(const int* __restrict__ bktCur, int* __restrict__ bktOff, int K) {
    int lane = threadIdx.x;  // blockDim=64, grid=1
    int chunk = (K + 63) >> 6;
    int beg = lane * chunk;
    int end = beg + chunk; if (end > K) end = K;
    int s = 0;
    for (int i = beg; i < end; i++) s += bktCur[i];
    int incl = s;
#pragma unroll
    for (int off = 1; off < 64; off <<= 1) {
        int v = __shfl_up(incl, off);
        if (lane >= off) incl += v;
    }
    int run = incl - s;
    for (int i = beg; i < end; i++) { bktOff[i] = run; run += bktCur[i]; }
    if (end == K) bktOff[K] = run;
}

// ---------------- CSR build, phase B (R10 verbatim) ----------------
__global__ __launch_bounds__(256) void k_bktB(const int* __restrict__ bktCur,
                                              const int* __restrict__ bktOff,
                                              const int2* __restrict__ bktbuf,
                                              int* __restrict__ rowp, int2* __restrict__ slotv,
                                              int N, int E, int K) {
    __shared__ int lhist[256];
    __shared__ int lrow[257];
    __shared__ int2 lslot[MAXB + 256];
    int k = blockIdx.x;
    int tid = threadIdx.x;
    int n0 = k << BKT_SHIFT;
    int nn = N - n0; if (nn > 256) nn = 256;
    int cnt = bktCur[k];
    int gbase = bktOff[k] + n0;
    lhist[tid] = 0;
    __syncthreads();
    const int2* rec = bktbuf + (size_t)k * MAXB;
    for (int i = tid; i < cnt; i += 256)
        atomicAdd(&lhist[(rec[i].x >> 16) & 255], 1);
    __syncthreads();
    if (tid == 0) {
        int r = 0;
        for (int i = 0; i < nn; i++) { lrow[i] = r; r += lhist[i] + 1; }
        lrow[nn] = r;
    }
    __syncthreads();
    if (tid < nn) {
        int lr = lrow[tid];
        rowp[n0 + tid] = gbase + lr;
        lslot[lr] = make_int2(n0 + tid, -1);
        lhist[tid] = lr + 1;
    }
    if (k == 0 && tid == 0) rowp[N] = E + N;
    __syncthreads();
    for (int i = tid; i < cnt; i += 256) {
        int2 rv = rec[i];
        int dl = (rv.x >> 16) & 255;
        int p = atomicAdd(&lhist[dl], 1);
        lslot[p] = make_int2(rv.x & 0xFFFF, rv.y);
    }
    __syncthreads();
    int tot = cnt + nn;
    for (int i = tid; i < tot; i += 256)
        slotv[gbase + i] = lslot[i];
}

// ---------------- conv1 + node2 fused: 1 node/wave, no max pass ----------------
// m = leaky(maxAS_h + ad_n) >= all per-edge logits (leaky monotone); softmax
// ratio is m-invariant, so numerics match the reference to fp rounding.
__global__ void k_conv1(const int* __restrict__ rowp, const int2* __restrict__ slotv,
                        const float* __restrict__ a_src, const float* __restrict__ a_dst,
                        const float* __restrict__ h1, const float* __restrict__ b1,
                        const float* __restrict__ W2, const float* __restrict__ as2,
                        const float* __restrict__ ad2,
                        float* __restrict__ h2, float* __restrict__ a_src2,
                        float* __restrict__ a_dst2, const unsigned* __restrict__ amax, int N) {
    int lane = threadIdx.x & 63;
    int n = __builtin_amdgcn_readfirstlane((int)((blockIdx.x * blockDim.x + threadIdx.x) >> 6));
    if (n >= N) return;
    int sub = lane & 31;
    int eslot = lane >> 5;
    int hh = sub >> 4;
    int beg = rowp[n], end = rowp[n + 1];
    float2 adv = *(const float2*)(a_dst + 2 * (size_t)n);
    float mxA = decf(amax[0]), mxB = decf(amax[1]);
    float m = hh ? lrelu(mxB + adv.y) : lrelu(mxA + adv.x);
    float ad = hh ? adv.y : adv.x;
    // 2 edges/iter, records read at wave-uniform addresses (scalar)
    float denom = 0.f, acc = 0.f;
#pragma unroll 4
    for (int j = beg; j < end; j += 2) {
        int2 sv0 = slotv[j];
        int2 sv1 = slotv[j + 1];          // may over-read 1 record; masked below
        int s0 = sv0.x & 0xFFFF, s1 = sv1.x & 0xFFFF;
        float2 a0 = *(const float2*)(a_src + 2 * (size_t)s0);
        float2 a1 = *(const float2*)(a_src + 2 * (size_t)s1);
        int s = eslot ? s1 : s0;
        float av = hh ? (eslot ? a1.y : a0.y) : (eslot ? a1.x : a0.x);
        float t = lrelu(av + ad);
        float wgt = __expf(t - m);
        if (j + eslot >= end) wgt = 0.f;
        acc += wgt * h1[s * 32 + sub];
        denom += wgt;
    }
    acc += __shfl_xor(acc, 32);
    denom += __shfl_xor(denom, 32);
    float ov = fmaxf(acc / denom + b1[sub], 0.f);   // out1[n][sub], both halves hold it
    // node2: h2[n][lane] = sum_k ov(k) * W2[k][lane]
    float acc2 = 0.f;
#pragma unroll
    for (int k = 0; k < 32; k++) acc2 += __shfl(ov, k, 32) * W2[k * 64 + lane];
    h2[(size_t)n * 64 + lane] = acc2;
    float p = acc2 * as2[lane];
    float q = acc2 * ad2[lane];
#pragma unroll
    for (int off = 16; off >= 1; off >>= 1) {
        p += __shfl_xor(p, off);
        q += __shfl_xor(q, off);
    }
    if ((lane & 31) == 0) {
        a_src2[n * 2 + (lane >> 5)] = p;
        a_dst2[n * 2 + (lane >> 5)] = q;
    }
}

// ---------------- conv2 + fc1 fused: 1 node/wave, no max pass ----------------
__global__ void k_conv2(const int* __restrict__ rowp, const int2* __restrict__ slotv,
                        const float* __restrict__ a_src, const float* __restrict__ a_dst,
                        const float* __restrict__ h2, const float* __restrict__ b2,
                        const float* __restrict__ fw1, const float* __restrict__ fb1,
                        float* __restrict__ g, const unsigned* __restrict__ amax, int N) {
    int lane = threadIdx.x & 63;
    int n = __builtin_amdgcn_readfirstlane((int)((blockIdx.x * blockDim.x + threadIdx.x) >> 6));
    if (n >= N) return;
    int hh = lane >> 5;
    int beg = rowp[n], end = rowp[n + 1];
    float2 adv = *(const float2*)(a_dst + 2 * (size_t)n);
    float mxA = decf(amax[0]), mxB = decf(amax[1]);
    float m = hh ? lrelu(mxB + adv.y) : lrelu(mxA + adv.x);
    float ad = hh ? adv.y : adv.x;
    float denom = 0.f, acc = 0.f;
#pragma unroll 4
    for (int j = beg; j < end; j++) {
        int s = slotv[j].x;
        float2 as = *(const float2*)(a_src + 2 * (size_t)s);
        float t = lrelu((hh ? as.y : as.x) + ad);
        float wgt = __expf(t - m);
        acc += wgt * h2[(size_t)s * 64 + lane];
        denom += wgt;
    }
    float res = fmaxf(acc / denom + b2[lane], 0.f);   // hfin[n][lane], never stored
    // fc1: g[n][lane] = 0.5*fb1[lane] + sum_k res(k) * fw1[k][lane]
    float gv = 0.5f * fb1[lane];
#pragma unroll
    for (int k = 0; k < 64; k++) gv += __shfl(res, k) * fw1[k * 64 + lane];
    g[(size_t)n * 64 + lane] = gv;
}

// ---------------- edge head v4: thread-per-CSR-slot (R10 verbatim) ----------------
__global__ void k_head4(const int* __restrict__ rowp, const int2* __restrict__ slotv,
                        const float* __restrict__ g,
                        const float* __restrict__ w2, const float* __restrict__ b2,
                        float* __restrict__ out, int M, int N) {
    int t = blockIdx.x * blockDim.x + threadIdx.x;
    if (t >= M) return;
    int2 sv = slotv[t];
    int id = sv.y;
    if (id < 0) return;
    int lo = 0, hi = N;
    while (hi - lo > 1) {
        int mid = (lo + hi) >> 1;
        if (rowp[mid] <= t) lo = mid; else hi = mid;
    }
    int n = lo;
    int r = sv.x;
    const float4* gr = (const float4*)(g + (size_t)r * 64);
    const float4* gc = (const float4*)(g + (size_t)n * 64);
    float o = b2[0];
#pragma unroll
    for (int q = 0; q < 16; q++) {
        float4 a = gr[q], b = gc[q];
        o += fmaxf(a.x + b.x, 0.f) * w2[4 * q + 0];
        o += fmaxf(a.y + b.y, 0.f) * w2[4 * q + 1];
        o += fmaxf(a.z + b.z, 0.f) * w2[4 * q + 2];
        o += fmaxf(a.w + b.w, 0.f) * w2[4 * q + 3];
    }
    out[id] = o;
}

extern "C" void kernel_launch(void* const* d_in, const int* in_sizes, int n_in,
                              void* d_out, int out_size, void* d_ws, size_t ws_size,
                              hipStream_t stream) {
    const float* x   = (const float*)d_in[0];
    const int*   ei  = (const int*)d_in[1];
    const float* W1  = (const float*)d_in[2];
    const float* as1 = (const float*)d_in[3];
    const float* ad1 = (const float*)d_in[4];
    const float* b1  = (const float*)d_in[5];
    const float* W2  = (const float*)d_in[6];
    const float* as2 = (const float*)d_in[7];
    const float* ad2 = (const float*)d_in[8];
    const float* b2  = (const float*)d_in[9];
    const float* fw1 = (const float*)d_in[10];
    const float* fb1 = (const float*)d_in[11];
    const float* fw2 = (const float*)d_in[12];
    const float* fb2 = (const float*)d_in[13];
    float* out = (float*)d_out;

    int N = in_sizes[0] / 8;
    int E = in_sizes[1] / 2;
    int M = E + N;
    int K = (N + 255) >> BKT_SHIFT;

    // ---- workspace layout (R10 map + 4-uint amax after bktCur) ----
    float* h1   = (float*)d_ws;
    float* asr1 = h1   + (size_t)N * 32;
    float* adt1 = asr1 + (size_t)N * 2;
    float* out1 = adt1 + (size_t)N * 2;   // bktbuf home only
    float* h2   = out1 + (size_t)N * 32;
    float* asr2 = h2   + (size_t)N * 64;
    float* adt2 = asr2 + (size_t)N * 2;
    int*   rowp = (int*)(adt2 + (size_t)N * 2);
    int2*  slotv = (int2*)(rowp + ((N + 2) & ~1));
    int*   bktCur = (int*)(slotv + M);
    unsigned* amax = (unsigned*)(bktCur + 256);   // [0,1]=layer1, [2,3]=layer2
    int*   bktOff = (int*)(amax + 4);
    int2*  bktbuf = (int2*)out1;
    float* g    = (float*)d_ws;           // 64N floats over region A (dead post-conv1)

    int B = 256;
    k_node1<<<(N + B - 1) / B, B, 0, stream>>>(x, W1, as1, ad1, h1, asr1, adt1, N);
    hipMemsetAsync(bktCur, 0, 260 * sizeof(int), stream);   // bktCur + amax (enc 0 = -inf)
    k_amax<<<64, 256, 0, stream>>>(asr1, amax, N);
    k_bktA<<<(E + EPB - 1) / EPB, 256, 0, stream>>>(ei, bktCur, bktbuf, E, K);
    k_bktscan<<<1, 64, 0, stream>>>(bktCur, bktOff, K);
    k_bktB<<<K, 256, 0, stream>>>(bktCur, bktOff, bktbuf, rowp, slotv, N, E, K);
    {
        long long thr = (long long)N * 64;
        k_conv1<<<(int)((thr + B - 1) / B), B, 0, stream>>>(rowp, slotv, asr1, adt1, h1, b1,
                                                            W2, as2, ad2, h2, asr2, adt2,
                                                            amax, N);
    }
    k_amax<<<64, 256, 0, stream>>>(asr2, amax + 2, N);
    {
        long long thr = (long long)N * 64;
        k_conv2<<<(int)((thr + B - 1) / B), B, 0, stream>>>(rowp, slotv, asr2, adt2, h2, b2,
                                                            fw1, fb1, g, amax + 2, N);
    }
    k_head4<<<(M + B - 1) / B, B, 0, stream>>>(rowp, slotv, g, fw2, fb2, out, M, N);
}

// Round 12
// 299.911 us; speedup vs baseline: 1.2076x; 1.2076x over previous
//
#include <hip/hip_runtime.h>
#include <hip/hip_fp16.h>
#include <math.h>

#define NEG_SLOPE 0.2f
#define BKT_SHIFT 8            // 256 nodes per bucket
#define EPB 8192               // edges per phase-A block
#define MAXB 10240             // record capacity per bucket region

// ---------------- node transform for conv1: h1(fp16) = x@W1, a_src1, a_dst1 ----------------
__global__ void k_node1(const float* __restrict__ x, const float* __restrict__ W1,
                        const float* __restrict__ as1, const float* __restrict__ ad1,
                        __half* __restrict__ h1h, float* __restrict__ a_src1,
                        float* __restrict__ a_dst1, int N) {
    int n = blockIdx.x * blockDim.x + threadIdx.x;
    if (n >= N) return;
    float xv[8];
#pragma unroll
    for (int k = 0; k < 8; k++) xv[k] = x[n * 8 + k];
    float h[32];
#pragma unroll
    for (int j = 0; j < 32; j++) {
        float acc = 0.f;
#pragma unroll
        for (int k = 0; k < 8; k++) acc += xv[k] * W1[k * 32 + j];
        h[j] = acc;
        h1h[n * 32 + j] = __float2half(acc);
    }
#pragma unroll
    for (int hh = 0; hh < 2; hh++) {
        float s = 0.f, d = 0.f;
#pragma unroll
        for (int c = 0; c < 16; c++) {
            s += h[hh * 16 + c] * as1[hh * 16 + c];
            d += h[hh * 16 + c] * ad1[hh * 16 + c];
        }
        a_src1[n * 2 + hh] = s;
        a_dst1[n * 2 + hh] = d;
    }
}

// ---------------- CSR build, phase A (R10 verbatim) ----------------
__global__ __launch_bounds__(256) void k_bktA(const int* __restrict__ ei,
                                              int* __restrict__ bktCur,
                                              int2* __restrict__ bktbuf, int E, int K) {
    __shared__ int bh[256];
    __shared__ int bbase[256];
    __shared__ int loff[256];
    __shared__ int2 staged[EPB];
    __shared__ int gptr[EPB];
    int tid = threadIdx.x;
    int e0 = blockIdx.x * EPB;
    int e1 = e0 + EPB; if (e1 > E) e1 = E;
    int cnt = e1 - e0;
    bh[tid] = 0;
    __syncthreads();
    for (int i = e0 + tid; i < e1; i += 256)
        atomicAdd(&bh[ei[E + i] >> BKT_SHIFT], 1);
    __syncthreads();
    if (tid == 0) {
        int r = 0;
        for (int b = 0; b < K; b++) { loff[b] = r; r += bh[b]; }
    }
    if (tid < K) {
        int c = bh[tid];
        bbase[tid] = c > 0 ? atomicAdd(&bktCur[tid], c) : 0;
    }
    __syncthreads();
    bh[tid] = 0;
    __syncthreads();
    for (int i = e0 + tid; i < e1; i += 256) {
        int s = ei[i], d = ei[E + i];
        int b = d >> BKT_SHIFT, dl = d & 255;
        int r = atomicAdd(&bh[b], 1);
        int lp = loff[b] + r;
        staged[lp] = make_int2(s | (dl << 16), i);
        gptr[lp] = b * MAXB + bbase[b] + r;
    }
    __syncthreads();
    for (int i = tid; i < cnt; i += 256)
        bktbuf[gptr[i]] = staged[i];
}

// ---------------- bucket-size exclusive scan (R10 verbatim) ----------------
__global__ void k_bktscan(const int* __restrict__ bktCur, int* __restrict__ bktOff, int K) {
    int lane = threadIdx.x;  // blockDim=64, grid=1
    int chunk = (K + 63) >> 6;
    int beg = lane * chunk;
    int end = beg + chunk; if (end > K) end = K;
    int s = 0;
    for (int i = beg; i < end; i++) s += bktCur[i];
    int incl = s;
#pragma unroll
    for (int off = 1; off < 64; off <<= 1) {
        int v = __shfl_up(incl, off);
        if (lane >= off) incl += v;
    }
    int run = incl - s;
    for (int i = beg; i < end; i++) { bktOff[i] = run; run += bktCur[i]; }
    if (end == K) bktOff[K] = run;
}

// ---------------- CSR build, phase B (R10 verbatim) ----------------
__global__ __launch_bounds__(256) void k_bktB(const int* __restrict__ bktCur,
                                              const int* __restrict__ bktOff,
                                              const int2* __restrict__ bktbuf,
                                              int* __restrict__ rowp, int2* __restrict__ slotv,
                                              int N, int E, int K) {
    __shared__ int lhist[256];
    __shared__ int lrow[257];
    __shared__ int2 lslot[MAXB + 256];
    int k = blockIdx.x;
    int tid = threadIdx.x;
    int n0 = k << BKT_SHIFT;
    int nn = N - n0; if (nn > 256) nn = 256;
    int cnt = bktCur[k];
    int gbase = bktOff[k] + n0;
    lhist[tid] = 0;
    __syncthreads();
    const int2* rec = bktbuf + (size_t)k * MAXB;
    for (int i = tid; i < cnt; i += 256)
        atomicAdd(&lhist[(rec[i].x >> 16) & 255], 1);
    __syncthreads();
    if (tid == 0) {
        int r = 0;
        for (int i = 0; i < nn; i++) { lrow[i] = r; r += lhist[i] + 1; }
        lrow[nn] = r;
    }
    __syncthreads();
    if (tid < nn) {
        int lr = lrow[tid];
        rowp[n0 + tid] = gbase + lr;
        lslot[lr] = make_int2(n0 + tid, -1);
        lhist[tid] = lr + 1;
    }
    if (k == 0 && tid == 0) rowp[N] = E + N;
    __syncthreads();
    for (int i = tid; i < cnt; i += 256) {
        int2 rv = rec[i];
        int dl = (rv.x >> 16) & 255;
        int p = atomicAdd(&lhist[dl], 1);
        lslot[p] = make_int2(rv.x & 0xFFFF, rv.y);
    }
    __syncthreads();
    int tot = cnt + nn;
    for (int i = tid; i < tot; i += 256)
        slotv[gbase + i] = lslot[i];
}

// ---------------- conv1 + node2 fused: 1 node/wave, two-pass (R10 structure, h1 fp16) ----------------
__global__ void k_conv1(const int* __restrict__ rowp, const int2* __restrict__ slotv,
                        const float* __restrict__ a_src, const float* __restrict__ a_dst,
                        const __half* __restrict__ h1h, const float* __restrict__ b1,
                        const float* __restrict__ W2, const float* __restrict__ as2,
                        const float* __restrict__ ad2,
                        __half* __restrict__ h2h, float* __restrict__ a_src2,
                        float* __restrict__ a_dst2, int N) {
    int lane = threadIdx.x & 63;
    int n = __builtin_amdgcn_readfirstlane((int)((blockIdx.x * blockDim.x + threadIdx.x) >> 6));
    if (n >= N) return;
    int sub = lane & 31;
    int eslot = lane >> 5;
    int hh = sub >> 4;
    int beg = rowp[n], end = rowp[n + 1];
    float2 adv = *(const float2*)(a_dst + 2 * (size_t)n);
    // pass 1: exact per-head max, 32-lane strided (halves duplicate) — also warms L2
    float mA = -1e30f, mB = -1e30f;
    for (int i = beg + sub; i < end; i += 32) {
        int s = ((const int*)slotv)[2 * i];
        float2 as = *(const float2*)(a_src + 2 * (size_t)s);
        float tA = as.x + adv.x; tA = fmaxf(tA, NEG_SLOPE * tA);
        float tB = as.y + adv.y; tB = fmaxf(tB, NEG_SLOPE * tB);
        mA = fmaxf(mA, tA); mB = fmaxf(mB, tB);
    }
#pragma unroll
    for (int off = 16; off >= 1; off >>= 1) {
        mA = fmaxf(mA, __shfl_xor(mA, off));
        mB = fmaxf(mB, __shfl_xor(mB, off));
    }
    float m = hh ? mB : mA;
    float ad = hh ? adv.y : adv.x;
    // pass 2: 2 edges/iter, records read at wave-uniform addresses (scalar)
    float denom = 0.f, acc = 0.f;
#pragma unroll 4
    for (int j = beg; j < end; j += 2) {
        int2 sv0 = slotv[j];
        int2 sv1 = slotv[j + 1];          // may over-read 1 record; masked below
        int s0 = sv0.x & 0xFFFF, s1 = sv1.x & 0xFFFF;
        float2 a0 = *(const float2*)(a_src + 2 * (size_t)s0);
        float2 a1 = *(const float2*)(a_src + 2 * (size_t)s1);
        int s = eslot ? s1 : s0;
        float av = hh ? (eslot ? a1.y : a0.y) : (eslot ? a1.x : a0.x);
        float t = av + ad;
        t = fmaxf(t, NEG_SLOPE * t);
        float wgt = __expf(t - m);
        if (j + eslot >= end) wgt = 0.f;
        acc += wgt * __half2float(h1h[s * 32 + sub]);
        denom += wgt;
    }
    acc += __shfl_xor(acc, 32);
    denom += __shfl_xor(denom, 32);
    float ov = fmaxf(acc / denom + b1[sub], 0.f);   // out1[n][sub], both halves hold it
    // node2: h2[n][lane] = sum_k ov(k) * W2[k][lane]
    float acc2 = 0.f;
#pragma unroll
    for (int k = 0; k < 32; k++) acc2 += __shfl(ov, k, 32) * W2[k * 64 + lane];
    h2h[(size_t)n * 64 + lane] = __float2half(acc2);
    float p = acc2 * as2[lane];
    float q = acc2 * ad2[lane];
#pragma unroll
    for (int off = 16; off >= 1; off >>= 1) {
        p += __shfl_xor(p, off);
        q += __shfl_xor(q, off);
    }
    if ((lane & 31) == 0) {
        a_src2[n * 2 + (lane >> 5)] = p;
        a_dst2[n * 2 + (lane >> 5)] = q;
    }
}

// ---------------- conv2 + fc1 fused: 1 node/wave, two-pass (R10 structure, h2 fp16) ----------------
__global__ void k_conv2(const int* __restrict__ rowp, const int2* __restrict__ slotv,
                        const float* __restrict__ a_src, const float* __restrict__ a_dst,
                        const __half* __restrict__ h2h, const float* __restrict__ b2,
                        const float* __restrict__ fw1, const float* __restrict__ fb1,
                        float* __restrict__ g, int N) {
    int lane = threadIdx.x & 63;
    int n = __builtin_amdgcn_readfirstlane((int)((blockIdx.x * blockDim.x + threadIdx.x) >> 6));
    if (n >= N) return;
    int hh = lane >> 5;
    int beg = rowp[n], end = rowp[n + 1];
    float2 adv = *(const float2*)(a_dst + 2 * (size_t)n);
    // pass 1: exact per-head max, 64-lane strided — also warms L2
    float mA = -1e30f, mB = -1e30f;
    for (int i = beg + lane; i < end; i += 64) {
        int s = ((const int*)slotv)[2 * i];
        float2 as = *(const float2*)(a_src + 2 * (size_t)s);
        float tA = as.x + adv.x; tA = fmaxf(tA, NEG_SLOPE * tA);
        float tB = as.y + adv.y; tB = fmaxf(tB, NEG_SLOPE * tB);
        mA = fmaxf(mA, tA); mB = fmaxf(mB, tB);
    }
#pragma unroll
    for (int off = 32; off >= 1; off >>= 1) {
        mA = fmaxf(mA, __shfl_xor(mA, off));
        mB = fmaxf(mB, __shfl_xor(mB, off));
    }
    float m = hh ? mB : mA;
    float ad = hh ? adv.y : adv.x;
    // pass 2: 1 edge/iter, scalar record + a_src reads
    float denom = 0.f, acc = 0.f;
#pragma unroll 4
    for (int j = beg; j < end; j++) {
        int s = slotv[j].x;
        float2 as = *(const float2*)(a_src + 2 * (size_t)s);
        float t = (hh ? as.y : as.x) + ad;
        t = fmaxf(t, NEG_SLOPE * t);
        float wgt = __expf(t - m);
        acc += wgt * __half2float(h2h[(size_t)s * 64 + lane]);
        denom += wgt;
    }
    float res = fmaxf(acc / denom + b2[lane], 0.f);   // hfin[n][lane], never stored
    // fc1: g[n][lane] = 0.5*fb1[lane] + sum_k res(k) * fw1[k][lane]
    float gv = 0.5f * fb1[lane];
#pragma unroll
    for (int k = 0; k < 64; k++) gv += __shfl(res, k) * fw1[k * 64 + lane];
    g[(size_t)n * 64 + lane] = gv;
}

// ---------------- edge head v4: thread-per-CSR-slot (R10 verbatim) ----------------
__global__ void k_head4(const int* __restrict__ rowp, const int2* __restrict__ slotv,
                        const float* __restrict__ g,
                        const float* __restrict__ w2, const float* __restrict__ b2,
                        float* __restrict__ out, int M, int N) {
    int t = blockIdx.x * blockDim.x + threadIdx.x;
    if (t >= M) return;
    int2 sv = slotv[t];
    int id = sv.y;
    if (id < 0) return;
    int lo = 0, hi = N;
    while (hi - lo > 1) {
        int mid = (lo + hi) >> 1;
        if (rowp[mid] <= t) lo = mid; else hi = mid;
    }
    int n = lo;
    int r = sv.x;
    const float4* gr = (const float4*)(g + (size_t)r * 64);
    const float4* gc = (const float4*)(g + (size_t)n * 64);
    float o = b2[0];
#pragma unroll
    for (int q = 0; q < 16; q++) {
        float4 a = gr[q], b = gc[q];
        o += fmaxf(a.x + b.x, 0.f) * w2[4 * q + 0];
        o += fmaxf(a.y + b.y, 0.f) * w2[4 * q + 1];
        o += fmaxf(a.z + b.z, 0.f) * w2[4 * q + 2];
        o += fmaxf(a.w + b.w, 0.f) * w2[4 * q + 3];
    }
    out[id] = o;
}

extern "C" void kernel_launch(void* const* d_in, const int* in_sizes, int n_in,
                              void* d_out, int out_size, void* d_ws, size_t ws_size,
                              hipStream_t stream) {
    const float* x   = (const float*)d_in[0];
    const int*   ei  = (const int*)d_in[1];
    const float* W1  = (const float*)d_in[2];
    const float* as1 = (const float*)d_in[3];
    const float* ad1 = (const float*)d_in[4];
    const float* b1  = (const float*)d_in[5];
    const float* W2  = (const float*)d_in[6];
    const float* as2 = (const float*)d_in[7];
    const float* ad2 = (const float*)d_in[8];
    const float* b2  = (const float*)d_in[9];
    const float* fw1 = (const float*)d_in[10];
    const float* fb1 = (const float*)d_in[11];
    const float* fw2 = (const float*)d_in[12];
    const float* fb2 = (const float*)d_in[13];
    float* out = (float*)d_out;

    int N = in_sizes[0] / 8;
    int E = in_sizes[1] / 2;
    int M = E + N;
    int K = (N + 255) >> BKT_SHIFT;

    // ---- workspace layout (R10 map; h-tables now fp16 inside their fp32-sized slots) ----
    float* h1slot = (float*)d_ws;                       // 32N floats; holds h1h (fp16, half used)
    float* asr1 = h1slot + (size_t)N * 32;
    float* adt1 = asr1 + (size_t)N * 2;
    float* out1 = adt1 + (size_t)N * 2;   // bktbuf home only
    float* h2slot = out1 + (size_t)N * 32;              // 64N floats; holds h2h (fp16, half used)
    float* asr2 = h2slot + (size_t)N * 64;
    float* adt2 = asr2 + (size_t)N * 2;
    int*   rowp = (int*)(adt2 + (size_t)N * 2);
    int2*  slotv = (int2*)(rowp + ((N + 2) & ~1));
    int*   bktCur = (int*)(slotv + M);
    int*   bktOff = bktCur + 256;
    int2*  bktbuf = (int2*)out1;          // 16.1MB <= out1+h2slot region (19.2MB), dead after bktB
    __half* h1h = (__half*)h1slot;
    __half* h2h = (__half*)h2slot;
    float* g    = (float*)d_ws;           // 64N floats over region A (dead post-conv1)

    int B = 256;
    k_node1<<<(N + B - 1) / B, B, 0, stream>>>(x, W1, as1, ad1, h1h, asr1, adt1, N);
    hipMemsetAsync(bktCur, 0, 256 * sizeof(int), stream);
    k_bktA<<<(E + EPB - 1) / EPB, 256, 0, stream>>>(ei, bktCur, bktbuf, E, K);
    k_bktscan<<<1, 64, 0, stream>>>(bktCur, bktOff, K);
    k_bktB<<<K, 256, 0, stream>>>(bktCur, bktOff, bktbuf, rowp, slotv, N, E, K);
    {
        long long thr = (long long)N * 64;
        k_conv1<<<(int)((thr + B - 1) / B), B, 0, stream>>>(rowp, slotv, asr1, adt1, h1h, b1,
                                                            W2, as2, ad2, h2h, asr2, adt2, N);
    }
    {
        long long thr = (long long)N * 64;
        k_conv2<<<(int)((thr + B - 1) / B), B, 0, stream>>>(rowp, slotv, asr2, adt2, h2h, b2,
                                                            fw1, fb1, g, N);
    }
    k_head4<<<(M + B - 1) / B, B, 0, stream>>>(rowp, slotv, g, fw2, fb2, out, M, N);
}

// Round 13
// 256.289 us; speedup vs baseline: 1.4132x; 1.1702x over previous
//
#include <hip/hip_runtime.h>
#include <hip/hip_fp16.h>
#include <math.h>

#define NEG_SLOPE 0.2f
#define BKT_SHIFT 8            // 256 nodes per bucket
#define EPB 8192               // edges per phase-A block
#define MAXB 10240             // record capacity per bucket region

// ---------------- node transform for conv1: h1(fp16) = x@W1, a_src1, a_dst1 ----------------
__global__ void k_node1(const float* __restrict__ x, const float* __restrict__ W1,
                        const float* __restrict__ as1, const float* __restrict__ ad1,
                        __half* __restrict__ h1h, float* __restrict__ a_src1,
                        float* __restrict__ a_dst1, int N) {
    int n = blockIdx.x * blockDim.x + threadIdx.x;
    if (n >= N) return;
    float xv[8];
#pragma unroll
    for (int k = 0; k < 8; k++) xv[k] = x[n * 8 + k];
    float h[32];
#pragma unroll
    for (int j = 0; j < 32; j++) {
        float acc = 0.f;
#pragma unroll
        for (int k = 0; k < 8; k++) acc += xv[k] * W1[k * 32 + j];
        h[j] = acc;
        h1h[n * 32 + j] = __float2half(acc);
    }
#pragma unroll
    for (int hh = 0; hh < 2; hh++) {
        float s = 0.f, d = 0.f;
#pragma unroll
        for (int c = 0; c < 16; c++) {
            s += h[hh * 16 + c] * as1[hh * 16 + c];
            d += h[hh * 16 + c] * ad1[hh * 16 + c];
        }
        a_src1[n * 2 + hh] = s;
        a_dst1[n * 2 + hh] = d;
    }
}

// ---------------- CSR build, phase A (R12 verbatim) ----------------
__global__ __launch_bounds__(256) void k_bktA(const int* __restrict__ ei,
                                              int* __restrict__ bktCur,
                                              int2* __restrict__ bktbuf, int E, int K) {
    __shared__ int bh[256];
    __shared__ int bbase[256];
    __shared__ int loff[256];
    __shared__ int2 staged[EPB];
    __shared__ int gptr[EPB];
    int tid = threadIdx.x;
    int e0 = blockIdx.x * EPB;
    int e1 = e0 + EPB; if (e1 > E) e1 = E;
    int cnt = e1 - e0;
    bh[tid] = 0;
    __syncthreads();
    for (int i = e0 + tid; i < e1; i += 256)
        atomicAdd(&bh[ei[E + i] >> BKT_SHIFT], 1);
    __syncthreads();
    if (tid == 0) {
        int r = 0;
        for (int b = 0; b < K; b++) { loff[b] = r; r += bh[b]; }
    }
    if (tid < K) {
        int c = bh[tid];
        bbase[tid] = c > 0 ? atomicAdd(&bktCur[tid], c) : 0;
    }
    __syncthreads();
    bh[tid] = 0;
    __syncthreads();
    for (int i = e0 + tid; i < e1; i += 256) {
        int s = ei[i], d = ei[E + i];
        int b = d >> BKT_SHIFT, dl = d & 255;
        int r = atomicAdd(&bh[b], 1);
        int lp = loff[b] + r;
        staged[lp] = make_int2(s | (dl << 16), i);
        gptr[lp] = b * MAXB + bbase[b] + r;
    }
    __syncthreads();
    for (int i = tid; i < cnt; i += 256)
        bktbuf[gptr[i]] = staged[i];
}

// ---------------- bucket-size exclusive scan (R12 verbatim) ----------------
__global__ void k_bktscan(const int* __restrict__ bktCur, int* __restrict__ bktOff, int K) {
    int lane = threadIdx.x;  // blockDim=64, grid=1
    int chunk = (K + 63) >> 6;
    int beg = lane * chunk;
    int end = beg + chunk; if (end > K) end = K;
    int s = 0;
    for (int i = beg; i < end; i++) s += bktCur[i];
    int incl = s;
#pragma unroll
    for (int off = 1; off < 64; off <<= 1) {
        int v = __shfl_up(incl, off);
        if (lane >= off) incl += v;
    }
    int run = incl - s;
    for (int i = beg; i < end; i++) { bktOff[i] = run; run += bktCur[i]; }
    if (end == K) bktOff[K] = run;
}

// ---------------- CSR build, phase B (R12 verbatim) ----------------
__global__ __launch_bounds__(256) void k_bktB(const int* __restrict__ bktCur,
                                              const int* __restrict__ bktOff,
                                              const int2* __restrict__ bktbuf,
                                              int* __restrict__ rowp, int2* __restrict__ slotv,
                                              int N, int E, int K) {
    __shared__ int lhist[256];
    __shared__ int lrow[257];
    __shared__ int2 lslot[MAXB + 256];
    int k = blockIdx.x;
    int tid = threadIdx.x;
    int n0 = k << BKT_SHIFT;
    int nn = N - n0; if (nn > 256) nn = 256;
    int cnt = bktCur[k];
    int gbase = bktOff[k] + n0;
    lhist[tid] = 0;
    __syncthreads();
    const int2* rec = bktbuf + (size_t)k * MAXB;
    for (int i = tid; i < cnt; i += 256)
        atomicAdd(&lhist[(rec[i].x >> 16) & 255], 1);
    __syncthreads();
    if (tid == 0) {
        int r = 0;
        for (int i = 0; i < nn; i++) { lrow[i] = r; r += lhist[i] + 1; }
        lrow[nn] = r;
    }
    __syncthreads();
    if (tid < nn) {
        int lr = lrow[tid];
        rowp[n0 + tid] = gbase + lr;
        lslot[lr] = make_int2(n0 + tid, -1);
        lhist[tid] = lr + 1;
    }
    if (k == 0 && tid == 0) rowp[N] = E + N;
    __syncthreads();
    for (int i = tid; i < cnt; i += 256) {
        int2 rv = rec[i];
        int dl = (rv.x >> 16) & 255;
        int p = atomicAdd(&lhist[dl], 1);
        lslot[p] = make_int2(rv.x & 0xFFFF, rv.y);
    }
    __syncthreads();
    int tot = cnt + nn;
    for (int i = tid; i < tot; i += 256)
        slotv[gbase + i] = lslot[i];
}

// ---------------- conv1 + node2 fused (R12 verbatim) ----------------
__global__ void k_conv1(const int* __restrict__ rowp, const int2* __restrict__ slotv,
                        const float* __restrict__ a_src, const float* __restrict__ a_dst,
                        const __half* __restrict__ h1h, const float* __restrict__ b1,
                        const float* __restrict__ W2, const float* __restrict__ as2,
                        const float* __restrict__ ad2,
                        __half* __restrict__ h2h, float* __restrict__ a_src2,
                        float* __restrict__ a_dst2, int N) {
    int lane = threadIdx.x & 63;
    int n = __builtin_amdgcn_readfirstlane((int)((blockIdx.x * blockDim.x + threadIdx.x) >> 6));
    if (n >= N) return;
    int sub = lane & 31;
    int eslot = lane >> 5;
    int hh = sub >> 4;
    int beg = rowp[n], end = rowp[n + 1];
    float2 adv = *(const float2*)(a_dst + 2 * (size_t)n);
    // pass 1: exact per-head max, 32-lane strided — also warms L2
    float mA = -1e30f, mB = -1e30f;
    for (int i = beg + sub; i < end; i += 32) {
        int s = ((const int*)slotv)[2 * i];
        float2 as = *(const float2*)(a_src + 2 * (size_t)s);
        float tA = as.x + adv.x; tA = fmaxf(tA, NEG_SLOPE * tA);
        float tB = as.y + adv.y; tB = fmaxf(tB, NEG_SLOPE * tB);
        mA = fmaxf(mA, tA); mB = fmaxf(mB, tB);
    }
#pragma unroll
    for (int off = 16; off >= 1; off >>= 1) {
        mA = fmaxf(mA, __shfl_xor(mA, off));
        mB = fmaxf(mB, __shfl_xor(mB, off));
    }
    float m = hh ? mB : mA;
    float ad = hh ? adv.y : adv.x;
    // pass 2: 2 edges/iter, records read at wave-uniform addresses (scalar)
    float denom = 0.f, acc = 0.f;
#pragma unroll 4
    for (int j = beg; j < end; j += 2) {
        int2 sv0 = slotv[j];
        int2 sv1 = slotv[j + 1];          // may over-read 1 record; masked below
        int s0 = sv0.x & 0xFFFF, s1 = sv1.x & 0xFFFF;
        float2 a0 = *(const float2*)(a_src + 2 * (size_t)s0);
        float2 a1 = *(const float2*)(a_src + 2 * (size_t)s1);
        int s = eslot ? s1 : s0;
        float av = hh ? (eslot ? a1.y : a0.y) : (eslot ? a1.x : a0.x);
        float t = av + ad;
        t = fmaxf(t, NEG_SLOPE * t);
        float wgt = __expf(t - m);
        if (j + eslot >= end) wgt = 0.f;
        acc += wgt * __half2float(h1h[s * 32 + sub]);
        denom += wgt;
    }
    acc += __shfl_xor(acc, 32);
    denom += __shfl_xor(denom, 32);
    float ov = fmaxf(acc / denom + b1[sub], 0.f);   // out1[n][sub], both halves hold it
    // node2: h2[n][lane] = sum_k ov(k) * W2[k][lane]
    float acc2 = 0.f;
#pragma unroll
    for (int k = 0; k < 32; k++) acc2 += __shfl(ov, k, 32) * W2[k * 64 + lane];
    h2h[(size_t)n * 64 + lane] = __float2half(acc2);
    float p = acc2 * as2[lane];
    float q = acc2 * ad2[lane];
#pragma unroll
    for (int off = 16; off >= 1; off >>= 1) {
        p += __shfl_xor(p, off);
        q += __shfl_xor(q, off);
    }
    if ((lane & 31) == 0) {
        a_src2[n * 2 + (lane >> 5)] = p;
        a_dst2[n * 2 + (lane >> 5)] = q;
    }
}

// ---------------- conv2 + fc1 fused (R12 structure; g output now fp16) ----------------
__global__ void k_conv2(const int* __restrict__ rowp, const int2* __restrict__ slotv,
                        const float* __restrict__ a_src, const float* __restrict__ a_dst,
                        const __half* __restrict__ h2h, const float* __restrict__ b2,
                        const float* __restrict__ fw1, const float* __restrict__ fb1,
                        __half* __restrict__ gh, int N) {
    int lane = threadIdx.x & 63;
    int n = __builtin_amdgcn_readfirstlane((int)((blockIdx.x * blockDim.x + threadIdx.x) >> 6));
    if (n >= N) return;
    int hh = lane >> 5;
    int beg = rowp[n], end = rowp[n + 1];
    float2 adv = *(const float2*)(a_dst + 2 * (size_t)n);
    // pass 1: exact per-head max, 64-lane strided — also warms L2
    float mA = -1e30f, mB = -1e30f;
    for (int i = beg + lane; i < end; i += 64) {
        int s = ((const int*)slotv)[2 * i];
        float2 as = *(const float2*)(a_src + 2 * (size_t)s);
        float tA = as.x + adv.x; tA = fmaxf(tA, NEG_SLOPE * tA);
        float tB = as.y + adv.y; tB = fmaxf(tB, NEG_SLOPE * tB);
        mA = fmaxf(mA, tA); mB = fmaxf(mB, tB);
    }
#pragma unroll
    for (int off = 32; off >= 1; off >>= 1) {
        mA = fmaxf(mA, __shfl_xor(mA, off));
        mB = fmaxf(mB, __shfl_xor(mB, off));
    }
    float m = hh ? mB : mA;
    float ad = hh ? adv.y : adv.x;
    // pass 2: 1 edge/iter, scalar record + a_src reads
    float denom = 0.f, acc = 0.f;
#pragma unroll 4
    for (int j = beg; j < end; j++) {
        int s = slotv[j].x;
        float2 as = *(const float2*)(a_src + 2 * (size_t)s);
        float t = (hh ? as.y : as.x) + ad;
        t = fmaxf(t, NEG_SLOPE * t);
        float wgt = __expf(t - m);
        acc += wgt * __half2float(h2h[(size_t)s * 64 + lane]);
        denom += wgt;
    }
    float res = fmaxf(acc / denom + b2[lane], 0.f);   // hfin[n][lane], never stored
    // fc1: g[n][lane] = 0.5*fb1[lane] + sum_k res(k) * fw1[k][lane]
    float gv = 0.5f * fb1[lane];
#pragma unroll
    for (int k = 0; k < 64; k++) gv += __shfl(res, k) * fw1[k * 64 + lane];
    gh[(size_t)n * 64 + lane] = __float2half(gv);
}

// ---------------- edge head v4: thread-per-CSR-slot, fp16 g rows (128B) ----------------
__global__ void k_head4(const int* __restrict__ rowp, const int2* __restrict__ slotv,
                        const __half* __restrict__ gh,
                        const float* __restrict__ w2, const float* __restrict__ b2,
                        float* __restrict__ out, int M, int N) {
    int t = blockIdx.x * blockDim.x + threadIdx.x;
    if (t >= M) return;
    int2 sv = slotv[t];
    int id = sv.y;
    if (id < 0) return;
    int lo = 0, hi = N;
    while (hi - lo > 1) {
        int mid = (lo + hi) >> 1;
        if (rowp[mid] <= t) lo = mid; else hi = mid;
    }
    int n = lo;
    int r = sv.x;
    const uint4* gr = (const uint4*)(gh + (size_t)r * 64);
    const uint4* gc = (const uint4*)(gh + (size_t)n * 64);
    float o = b2[0];
#pragma unroll
    for (int q = 0; q < 8; q++) {           // 8 × 16B = 64 halves
        uint4 ua = gr[q], ub = gc[q];
#pragma unroll
        for (int w = 0; w < 4; w++) {
            unsigned a32 = (&ua.x)[w], b32 = (&ub.x)[w];
            float2 fa = __half22float2(*(const __half2*)&a32);
            float2 fb = __half22float2(*(const __half2*)&b32);
            int j = q * 8 + w * 2;
            o += fmaxf(fa.x + fb.x, 0.f) * w2[j];
            o += fmaxf(fa.y + fb.y, 0.f) * w2[j + 1];
        }
    }
    out[id] = o;
}

extern "C" void kernel_launch(void* const* d_in, const int* in_sizes, int n_in,
                              void* d_out, int out_size, void* d_ws, size_t ws_size,
                              hipStream_t stream) {
    const float* x   = (const float*)d_in[0];
    const int*   ei  = (const int*)d_in[1];
    const float* W1  = (const float*)d_in[2];
    const float* as1 = (const float*)d_in[3];
    const float* ad1 = (const float*)d_in[4];
    const float* b1  = (const float*)d_in[5];
    const float* W2  = (const float*)d_in[6];
    const float* as2 = (const float*)d_in[7];
    const float* ad2 = (const float*)d_in[8];
    const float* b2  = (const float*)d_in[9];
    const float* fw1 = (const float*)d_in[10];
    const float* fb1 = (const float*)d_in[11];
    const float* fw2 = (const float*)d_in[12];
    const float* fb2 = (const float*)d_in[13];
    float* out = (float*)d_out;

    int N = in_sizes[0] / 8;
    int E = in_sizes[1] / 2;
    int M = E + N;
    int K = (N + 255) >> BKT_SHIFT;

    // ---- workspace layout (R12 map; g now fp16 over region A) ----
    float* h1slot = (float*)d_ws;                       // holds h1h (fp16)
    float* asr1 = h1slot + (size_t)N * 32;
    float* adt1 = asr1 + (size_t)N * 2;
    float* out1 = adt1 + (size_t)N * 2;   // bktbuf home only
    float* h2slot = out1 + (size_t)N * 32;              // holds h2h (fp16)
    float* asr2 = h2slot + (size_t)N * 64;
    float* adt2 = asr2 + (size_t)N * 2;
    int*   rowp = (int*)(adt2 + (size_t)N * 2);
    int2*  slotv = (int2*)(rowp + ((N + 2) & ~1));
    int*   bktCur = (int*)(slotv + M);
    int*   bktOff = bktCur + 256;
    int2*  bktbuf = (int2*)out1;          // dead after bktB
    __half* h1h = (__half*)h1slot;
    __half* h2h = (__half*)h2slot;
    __half* gh  = (__half*)d_ws;          // 64N halves over region A (dead post-conv1)

    int B = 256;
    k_node1<<<(N + B - 1) / B, B, 0, stream>>>(x, W1, as1, ad1, h1h, asr1, adt1, N);
    hipMemsetAsync(bktCur, 0, 256 * sizeof(int), stream);
    k_bktA<<<(E + EPB - 1) / EPB, 256, 0, stream>>>(ei, bktCur, bktbuf, E, K);
    k_bktscan<<<1, 64, 0, stream>>>(bktCur, bktOff, K);
    k_bktB<<<K, 256, 0, stream>>>(bktCur, bktOff, bktbuf, rowp, slotv, N, E, K);
    {
        long long thr = (long long)N * 64;
        k_conv1<<<(int)((thr + B - 1) / B), B, 0, stream>>>(rowp, slotv, asr1, adt1, h1h, b1,
                                                            W2, as2, ad2, h2h, asr2, adt2, N);
    }
    {
        long long thr = (long long)N * 64;
        k_conv2<<<(int)((thr + B - 1) / B), B, 0, stream>>>(rowp, slotv, asr2, adt2, h2h, b2,
                                                            fw1, fb1, gh, N);
    }
    k_head4<<<(M + B - 1) / B, B, 0, stream>>>(rowp, slotv, gh, fw2, fb2, out, M, N);
}

// Round 14
// 237.754 us; speedup vs baseline: 1.5234x; 1.0780x over previous
//
#include <hip/hip_runtime.h>
#include <hip/hip_fp16.h>
#include <math.h>

#define NEG_SLOPE 0.2f
#define BKT_SHIFT 8            // 256 nodes per bucket
#define EPB 8192               // edges per phase-A block
#define MAXB 10240             // record capacity per bucket region

// ---------------- node transform for conv1: h1(fp16) = x@W1, a_src1, a_dst1 ----------------
__global__ void k_node1(const float* __restrict__ x, const float* __restrict__ W1,
                        const float* __restrict__ as1, const float* __restrict__ ad1,
                        __half* __restrict__ h1h, float* __restrict__ a_src1,
                        float* __restrict__ a_dst1, int N) {
    int n = blockIdx.x * blockDim.x + threadIdx.x;
    if (n >= N) return;
    float xv[8];
#pragma unroll
    for (int k = 0; k < 8; k++) xv[k] = x[n * 8 + k];
    float h[32];
#pragma unroll
    for (int j = 0; j < 32; j++) {
        float acc = 0.f;
#pragma unroll
        for (int k = 0; k < 8; k++) acc += xv[k] * W1[k * 32 + j];
        h[j] = acc;
        h1h[n * 32 + j] = __float2half(acc);
    }
#pragma unroll
    for (int hh = 0; hh < 2; hh++) {
        float s = 0.f, d = 0.f;
#pragma unroll
        for (int c = 0; c < 16; c++) {
            s += h[hh * 16 + c] * as1[hh * 16 + c];
            d += h[hh * 16 + c] * ad1[hh * 16 + c];
        }
        a_src1[n * 2 + hh] = s;
        a_dst1[n * 2 + hh] = d;
    }
}

// ---------------- CSR build, phase A (R13 verbatim) ----------------
__global__ __launch_bounds__(256) void k_bktA(const int* __restrict__ ei,
                                              int* __restrict__ bktCur,
                                              int2* __restrict__ bktbuf, int E, int K) {
    __shared__ int bh[256];
    __shared__ int bbase[256];
    __shared__ int loff[256];
    __shared__ int2 staged[EPB];
    __shared__ int gptr[EPB];
    int tid = threadIdx.x;
    int e0 = blockIdx.x * EPB;
    int e1 = e0 + EPB; if (e1 > E) e1 = E;
    int cnt = e1 - e0;
    bh[tid] = 0;
    __syncthreads();
    for (int i = e0 + tid; i < e1; i += 256)
        atomicAdd(&bh[ei[E + i] >> BKT_SHIFT], 1);
    __syncthreads();
    if (tid == 0) {
        int r = 0;
        for (int b = 0; b < K; b++) { loff[b] = r; r += bh[b]; }
    }
    if (tid < K) {
        int c = bh[tid];
        bbase[tid] = c > 0 ? atomicAdd(&bktCur[tid], c) : 0;
    }
    __syncthreads();
    bh[tid] = 0;
    __syncthreads();
    for (int i = e0 + tid; i < e1; i += 256) {
        int s = ei[i], d = ei[E + i];
        int b = d >> BKT_SHIFT, dl = d & 255;
        int r = atomicAdd(&bh[b], 1);
        int lp = loff[b] + r;
        staged[lp] = make_int2(s | (dl << 16), i);
        gptr[lp] = b * MAXB + bbase[b] + r;
    }
    __syncthreads();
    for (int i = tid; i < cnt; i += 256)
        bktbuf[gptr[i]] = staged[i];
}

// ---------------- bucket-size exclusive scan (R13 verbatim) ----------------
__global__ void k_bktscan(const int* __restrict__ bktCur, int* __restrict__ bktOff, int K) {
    int lane = threadIdx.x;  // blockDim=64, grid=1
    int chunk = (K + 63) >> 6;
    int beg = lane * chunk;
    int end = beg + chunk; if (end > K) end = K;
    int s = 0;
    for (int i = beg; i < end; i++) s += bktCur[i];
    int incl = s;
#pragma unroll
    for (int off = 1; off < 64; off <<= 1) {
        int v = __shfl_up(incl, off);
        if (lane >= off) incl += v;
    }
    int run = incl - s;
    for (int i = beg; i < end; i++) { bktOff[i] = run; run += bktCur[i]; }
    if (end == K) bktOff[K] = run;
}

// ---------------- CSR build, phase B (R13 verbatim) ----------------
__global__ __launch_bounds__(256) void k_bktB(const int* __restrict__ bktCur,
                                              const int* __restrict__ bktOff,
                                              const int2* __restrict__ bktbuf,
                                              int* __restrict__ rowp, int2* __restrict__ slotv,
                                              int N, int E, int K) {
    __shared__ int lhist[256];
    __shared__ int lrow[257];
    __shared__ int2 lslot[MAXB + 256];
    int k = blockIdx.x;
    int tid = threadIdx.x;
    int n0 = k << BKT_SHIFT;
    int nn = N - n0; if (nn > 256) nn = 256;
    int cnt = bktCur[k];
    int gbase = bktOff[k] + n0;
    lhist[tid] = 0;
    __syncthreads();
    const int2* rec = bktbuf + (size_t)k * MAXB;
    for (int i = tid; i < cnt; i += 256)
        atomicAdd(&lhist[(rec[i].x >> 16) & 255], 1);
    __syncthreads();
    if (tid == 0) {
        int r = 0;
        for (int i = 0; i < nn; i++) { lrow[i] = r; r += lhist[i] + 1; }
        lrow[nn] = r;
    }
    __syncthreads();
    if (tid < nn) {
        int lr = lrow[tid];
        rowp[n0 + tid] = gbase + lr;
        lslot[lr] = make_int2(n0 + tid, -1);
        lhist[tid] = lr + 1;
    }
    if (k == 0 && tid == 0) rowp[N] = E + N;
    __syncthreads();
    for (int i = tid; i < cnt; i += 256) {
        int2 rv = rec[i];
        int dl = (rv.x >> 16) & 255;
        int p = atomicAdd(&lhist[dl], 1);
        lslot[p] = make_int2(rv.x & 0xFFFF, rv.y);
    }
    __syncthreads();
    int tot = cnt + nn;
    for (int i = tid; i < tot; i += 256)
        slotv[gbase + i] = lslot[i];
}

// ---------------- conv1 + node2 fused: LDS edge-parallel weight staging ----------------
__global__ __launch_bounds__(256) void k_conv1(
        const int* __restrict__ rowp, const int2* __restrict__ slotv,
        const float* __restrict__ a_src, const float* __restrict__ a_dst,
        const __half* __restrict__ h1h, const float* __restrict__ b1,
        const float* __restrict__ W2, const float* __restrict__ as2,
        const float* __restrict__ ad2,
        __half* __restrict__ h2h, float* __restrict__ a_src2,
        float* __restrict__ a_dst2, int N) {
    __shared__ int   lsS[4][64];
    __shared__ float lsW[4][2][64];
    int tid = threadIdx.x;
    int lane = tid & 63;
    int wv = tid >> 6;
    int n = __builtin_amdgcn_readfirstlane((int)((blockIdx.x * blockDim.x + tid) >> 6));
    if (n >= N) return;
    int sub = lane & 31;
    int eslot = lane >> 5;
    int hh = sub >> 4;
    int beg = rowp[n], end = rowp[n + 1];
    float2 adv = *(const float2*)(a_dst + 2 * (size_t)n);
    // pass 1: exact per-head max, 64-lane strided
    float mA = -1e30f, mB = -1e30f;
    for (int i = beg + lane; i < end; i += 64) {
        int s = slotv[i].x;
        float2 as = *(const float2*)(a_src + 2 * (size_t)s);
        float tA = as.x + adv.x; tA = fmaxf(tA, NEG_SLOPE * tA);
        float tB = as.y + adv.y; tB = fmaxf(tB, NEG_SLOPE * tB);
        mA = fmaxf(mA, tA); mB = fmaxf(mB, tB);
    }
#pragma unroll
    for (int off = 32; off >= 1; off >>= 1) {
        mA = fmaxf(mA, __shfl_xor(mA, off));
        mB = fmaxf(mB, __shfl_xor(mB, off));
    }
    // pass 2: chunks of 64 edges
    float denom = 0.f, acc = 0.f;
    for (int j0 = beg; j0 < end; j0 += 64) {
        int idx = j0 + lane;
        bool valid = idx < end;
        int s = valid ? slotv[idx].x : 0;
        float2 as = valid ? *(const float2*)(a_src + 2 * (size_t)s)
                          : make_float2(0.f, 0.f);
        float tA = as.x + adv.x; tA = fmaxf(tA, NEG_SLOPE * tA);
        float tB = as.y + adv.y; tB = fmaxf(tB, NEG_SLOPE * tB);
        float wA = valid ? __expf(tA - mA) : 0.f;
        float wB = valid ? __expf(tB - mB) : 0.f;
        lsS[wv][lane] = s;
        lsW[wv][0][lane] = wA;
        lsW[wv][1][lane] = wB;
        float rA = wA, rB = wB;
#pragma unroll
        for (int off = 32; off >= 1; off >>= 1) {
            rA += __shfl_xor(rA, off);
            rB += __shfl_xor(rB, off);
        }
        denom += hh ? rB : rA;            // full-chunk denom (do NOT combine across slots)
        int cnt = end - j0; if (cnt > 64) cnt = 64;
#pragma unroll 4
        for (int jj = 0; jj < cnt; jj += 2) {
            int e = jj + eslot;           // invalid e has w=0 staged
            int sj = lsS[wv][e];
            float wgt = lsW[wv][hh][e];
            acc += wgt * __half2float(h1h[sj * 32 + sub]);
        }
    }
    acc += __shfl_xor(acc, 32);           // combine the 2 edge-slots
    float ov = fmaxf(acc / denom + b1[sub], 0.f);   // out1[n][sub]
    // node2: h2[n][lane] = sum_k ov(k) * W2[k][lane]
    float acc2 = 0.f;
#pragma unroll
    for (int k = 0; k < 32; k++) acc2 += __shfl(ov, k, 32) * W2[k * 64 + lane];
    h2h[(size_t)n * 64 + lane] = __float2half(acc2);
    float p = acc2 * as2[lane];
    float q = acc2 * ad2[lane];
#pragma unroll
    for (int off = 16; off >= 1; off >>= 1) {
        p += __shfl_xor(p, off);
        q += __shfl_xor(q, off);
    }
    if ((lane & 31) == 0) {
        a_src2[n * 2 + (lane >> 5)] = p;
        a_dst2[n * 2 + (lane >> 5)] = q;
    }
}

// ---------------- conv2 + fc1 fused: LDS edge-parallel weight staging ----------------
__global__ __launch_bounds__(256) void k_conv2(
        const int* __restrict__ rowp, const int2* __restrict__ slotv,
        const float* __restrict__ a_src, const float* __restrict__ a_dst,
        const __half* __restrict__ h2h, const float* __restrict__ b2,
        const float* __restrict__ fw1, const float* __restrict__ fb1,
        __half* __restrict__ gh, int N) {
    __shared__ int   lsS[4][64];
    __shared__ float lsW[4][2][64];
    int tid = threadIdx.x;
    int lane = tid & 63;
    int wv = tid >> 6;
    int n = __builtin_amdgcn_readfirstlane((int)((blockIdx.x * blockDim.x + tid) >> 6));
    if (n >= N) return;
    int hh = lane >> 5;
    int beg = rowp[n], end = rowp[n + 1];
    float2 adv = *(const float2*)(a_dst + 2 * (size_t)n);
    // pass 1: exact per-head max, 64-lane strided
    float mA = -1e30f, mB = -1e30f;
    for (int i = beg + lane; i < end; i += 64) {
        int s = slotv[i].x;
        float2 as = *(const float2*)(a_src + 2 * (size_t)s);
        float tA = as.x + adv.x; tA = fmaxf(tA, NEG_SLOPE * tA);
        float tB = as.y + adv.y; tB = fmaxf(tB, NEG_SLOPE * tB);
        mA = fmaxf(mA, tA); mB = fmaxf(mB, tB);
    }
#pragma unroll
    for (int off = 32; off >= 1; off >>= 1) {
        mA = fmaxf(mA, __shfl_xor(mA, off));
        mB = fmaxf(mB, __shfl_xor(mB, off));
    }
    // pass 2: chunks of 64 edges
    float denom = 0.f, acc = 0.f;
    for (int j0 = beg; j0 < end; j0 += 64) {
        int idx = j0 + lane;
        bool valid = idx < end;
        int s = valid ? slotv[idx].x : 0;
        float2 as = valid ? *(const float2*)(a_src + 2 * (size_t)s)
                          : make_float2(0.f, 0.f);
        float tA = as.x + adv.x; tA = fmaxf(tA, NEG_SLOPE * tA);
        float tB = as.y + adv.y; tB = fmaxf(tB, NEG_SLOPE * tB);
        float wA = valid ? __expf(tA - mA) : 0.f;
        float wB = valid ? __expf(tB - mB) : 0.f;
        lsS[wv][lane] = s;
        lsW[wv][0][lane] = wA;
        lsW[wv][1][lane] = wB;
        float rA = wA, rB = wB;
#pragma unroll
        for (int off = 32; off >= 1; off >>= 1) {
            rA += __shfl_xor(rA, off);
            rB += __shfl_xor(rB, off);
        }
        denom += hh ? rB : rA;
        int cnt = end - j0; if (cnt > 64) cnt = 64;
#pragma unroll 8
        for (int jj = 0; jj < cnt; jj++) {
            int sj = lsS[wv][jj];
            float wgt = lsW[wv][hh][jj];
            acc += wgt * __half2float(h2h[(size_t)sj * 64 + lane]);
        }
    }
    float res = fmaxf(acc / denom + b2[lane], 0.f);   // hfin[n][lane], never stored
    // fc1: g[n][lane] = 0.5*fb1[lane] + sum_k res(k) * fw1[k][lane]
    float gv = 0.5f * fb1[lane];
#pragma unroll
    for (int k = 0; k < 64; k++) gv += __shfl(res, k) * fw1[k * 64 + lane];
    gh[(size_t)n * 64 + lane] = __float2half(gv);
}

// ---------------- edge head v4: thread-per-CSR-slot, fp16 g rows (R13 verbatim) ----------------
__global__ void k_head4(const int* __restrict__ rowp, const int2* __restrict__ slotv,
                        const __half* __restrict__ gh,
                        const float* __restrict__ w2, const float* __restrict__ b2,
                        float* __restrict__ out, int M, int N) {
    int t = blockIdx.x * blockDim.x + threadIdx.x;
    if (t >= M) return;
    int2 sv = slotv[t];
    int id = sv.y;
    if (id < 0) return;
    int lo = 0, hi = N;
    while (hi - lo > 1) {
        int mid = (lo + hi) >> 1;
        if (rowp[mid] <= t) lo = mid; else hi = mid;
    }
    int n = lo;
    int r = sv.x;
    const uint4* gr = (const uint4*)(gh + (size_t)r * 64);
    const uint4* gc = (const uint4*)(gh + (size_t)n * 64);
    float o = b2[0];
#pragma unroll
    for (int q = 0; q < 8; q++) {           // 8 × 16B = 64 halves
        uint4 ua = gr[q], ub = gc[q];
#pragma unroll
        for (int w = 0; w < 4; w++) {
            unsigned a32 = (&ua.x)[w], b32 = (&ub.x)[w];
            float2 fa = __half22float2(*(const __half2*)&a32);
            float2 fb = __half22float2(*(const __half2*)&b32);
            int j = q * 8 + w * 2;
            o += fmaxf(fa.x + fb.x, 0.f) * w2[j];
            o += fmaxf(fa.y + fb.y, 0.f) * w2[j + 1];
        }
    }
    out[id] = o;
}

extern "C" void kernel_launch(void* const* d_in, const int* in_sizes, int n_in,
                              void* d_out, int out_size, void* d_ws, size_t ws_size,
                              hipStream_t stream) {
    const float* x   = (const float*)d_in[0];
    const int*   ei  = (const int*)d_in[1];
    const float* W1  = (const float*)d_in[2];
    const float* as1 = (const float*)d_in[3];
    const float* ad1 = (const float*)d_in[4];
    const float* b1  = (const float*)d_in[5];
    const float* W2  = (const float*)d_in[6];
    const float* as2 = (const float*)d_in[7];
    const float* ad2 = (const float*)d_in[8];
    const float* b2  = (const float*)d_in[9];
    const float* fw1 = (const float*)d_in[10];
    const float* fb1 = (const float*)d_in[11];
    const float* fw2 = (const float*)d_in[12];
    const float* fb2 = (const float*)d_in[13];
    float* out = (float*)d_out;

    int N = in_sizes[0] / 8;
    int E = in_sizes[1] / 2;
    int M = E + N;
    int K = (N + 255) >> BKT_SHIFT;

    // ---- workspace layout (R13 verbatim) ----
    float* h1slot = (float*)d_ws;                       // holds h1h (fp16)
    float* asr1 = h1slot + (size_t)N * 32;
    float* adt1 = asr1 + (size_t)N * 2;
    float* out1 = adt1 + (size_t)N * 2;   // bktbuf home only
    float* h2slot = out1 + (size_t)N * 32;              // holds h2h (fp16)
    float* asr2 = h2slot + (size_t)N * 64;
    float* adt2 = asr2 + (size_t)N * 2;
    int*   rowp = (int*)(adt2 + (size_t)N * 2);
    int2*  slotv = (int2*)(rowp + ((N + 2) & ~1));
    int*   bktCur = (int*)(slotv + M);
    int*   bktOff = bktCur + 256;
    int2*  bktbuf = (int2*)out1;          // dead after bktB
    __half* h1h = (__half*)h1slot;
    __half* h2h = (__half*)h2slot;
    __half* gh  = (__half*)d_ws;          // 64N halves over region A (dead post-conv1)

    int B = 256;
    k_node1<<<(N + B - 1) / B, B, 0, stream>>>(x, W1, as1, ad1, h1h, asr1, adt1, N);
    hipMemsetAsync(bktCur, 0, 256 * sizeof(int), stream);
    k_bktA<<<(E + EPB - 1) / EPB, 256, 0, stream>>>(ei, bktCur, bktbuf, E, K);
    k_bktscan<<<1, 64, 0, stream>>>(bktCur, bktOff, K);
    k_bktB<<<K, 256, 0, stream>>>(bktCur, bktOff, bktbuf, rowp, slotv, N, E, K);
    {
        long long thr = (long long)N * 64;
        k_conv1<<<(int)((thr + B - 1) / B), B, 0, stream>>>(rowp, slotv, asr1, adt1, h1h, b1,
                                                            W2, as2, ad2, h2h, asr2, adt2, N);
    }
    {
        long long thr = (long long)N * 64;
        k_conv2<<<(int)((thr + B - 1) / B), B, 0, stream>>>(rowp, slotv, asr2, adt2, h2h, b2,
                                                            fw1, fb1, gh, N);
    }
    k_head4<<<(M + B - 1) / B, B, 0, stream>>>(rowp, slotv, gh, fw2, fb2, out, M, N);
}